// Round 17
// baseline (269.945 us; speedup 1.0000x reference)
//
#include <hip/hip_runtime.h>

#define L_SEQ 4096
#define DM    1024
#define NH    16
#define HD    64

typedef unsigned short ushort_t;
typedef __attribute__((ext_vector_type(8))) short bf16x8;
typedef __attribute__((ext_vector_type(4))) float f32x4;

__device__ inline unsigned short f2bf(float f) {
    union { float f; unsigned int u; } v; v.f = f;
    unsigned int r = v.u + 0x7fffu + ((v.u >> 16) & 1u);
    return (unsigned short)(r >> 16);
}

// pack two f32 -> two bf16 (RNE) in one instruction
__device__ inline unsigned cvt_pk_bf16(float lo, float hi) {
    unsigned w;
    asm("v_cvt_pk_bf16_f32 %0, %1, %2" : "=v"(w) : "v"(lo), "v"(hi));
    return w;
}

// raw v_exp_f32 (2^x); exact enough for our domain (args <= ~40; -1e30 -> 0)
__device__ inline float ex2(float x) {
#if __has_builtin(__builtin_amdgcn_exp2f)
    return __builtin_amdgcn_exp2f(x);
#else
    return exp2f(x);
#endif
}

// async global->LDS, 16B/lane. LDS dest = wave-uniform base + lane*16.
__device__ inline void load_lds16(const ushort_t* g, ushort_t* l) {
    __builtin_amdgcn_global_load_lds(
        (const __attribute__((address_space(1))) unsigned int*)g,
        (__attribute__((address_space(3))) unsigned int*)l, 16, 0, 0);
}

// ---------------------------------------------------------------------------
// Runtime input-dtype detection (bf16 vs fp32 global buffers). Verified R3.
// ---------------------------------------------------------------------------
__device__ inline bool detect_f32(const ushort_t* xraw) {
    __shared__ int s_flag;
    const int t = threadIdx.x;
    if (t < 64) {
        unsigned e = (xraw[2 * t] >> 7) & 0xFFu;
        unsigned long long m = __ballot(e >= 0x88u);
        if (t == 0) s_flag = (__popcll(m) >= 8) ? 1 : 0;
    }
    __syncthreads();
    return s_flag != 0;
}

// ---------------------------------------------------------------------------
// Fused converts: z=0..3 -> weight z transposed bf16 wT[n][k]; z=4 -> x bf16.
// grid (16,16,5) x 256 thr.
// ---------------------------------------------------------------------------
__global__ __launch_bounds__(256) void convert_all(const void* __restrict__ xv,
                                                   const void* __restrict__ w0,
                                                   const void* __restrict__ w1,
                                                   const void* __restrict__ w2,
                                                   const void* __restrict__ w3,
                                                   ushort_t* __restrict__ xb,
                                                   ushort_t* __restrict__ wT) {
    bool f32 = detect_f32((const ushort_t*)xv);
    const int z = blockIdx.z;
    const int t = threadIdx.x;

    if (z == 4) {
        const int B0 = (blockIdx.y * 16 + blockIdx.x) * 16384;
        #pragma unroll
        for (int it = 0; it < 8; ++it) {
            const int i = B0 + it * 2048 + t * 8;
            if (f32) {
                const float* xf = (const float*)xv;
                float4 v0 = *(const float4*)(xf + i);
                float4 v1 = *(const float4*)(xf + i + 4);
                uint4 u;
                u.x = cvt_pk_bf16(v0.x, v0.y);
                u.y = cvt_pk_bf16(v0.z, v0.w);
                u.z = cvt_pk_bf16(v1.x, v1.y);
                u.w = cvt_pk_bf16(v1.z, v1.w);
                *(uint4*)(xb + i) = u;
            } else {
                *(uint4*)(xb + i) = *(const uint4*)((const ushort_t*)xv + i);
            }
        }
        return;
    }

    const void* w = (z == 0) ? w0 : (z == 1) ? w1 : (z == 2) ? w2 : w3;
    ushort_t* out = wT + (size_t)z * (DM * DM);
    __shared__ ushort_t T[64][65];
    const int k0 = blockIdx.x * 64, n0 = blockIdx.y * 64;
    #pragma unroll
    for (int i = 0; i < 16; ++i) {
        int e = t + i * 256;
        int r = e >> 6, c = e & 63;
        T[r][c] = f32 ? f2bf(((const float*)w)[(size_t)(k0 + r) * DM + n0 + c])
                      : ((const ushort_t*)w)[(size_t)(k0 + r) * DM + n0 + c];
    }
    __syncthreads();
    #pragma unroll
    for (int i = 0; i < 16; ++i) {
        int e = t + i * 256;
        int d = e >> 6, l = e & 63;
        out[(size_t)(n0 + d) * DM + k0 + l] = T[l][d];
    }
}

// ---------------------------------------------------------------------------
// R11 GEMM (verified best): BK=64, single-buffered, 128x128 tile.
// cmode: 0 bf16 row-major, 1 f32 row-major, 2 bf16 transposed (Vt[d][L]).
// ---------------------------------------------------------------------------
__device__ inline void gemm128_body(const ushort_t* __restrict__ A,
                                    const ushort_t* __restrict__ Bt,
                                    void* __restrict__ Cv, int cmode,
                                    int m0, int n0) {
    constexpr int K = 1024, NOUT = 1024;
    __shared__ ushort_t As[128 * 64];   // [r][k], swizzled, 16 KB
    __shared__ ushort_t Bs[128 * 64];

    const int t = threadIdx.x, lane = t & 63, wave = t >> 6;
    const int l15 = lane & 15, quad = lane >> 4;
    const int mw = (wave >> 1) * 64, nw = (wave & 1) * 64;
    const int srow = lane >> 3;
    const int sgr  = (lane & 7) ^ (lane >> 3);
    const int swz  = l15 & 7;

    f32x4 acc[4][4] = {};

    for (int k0 = 0; k0 < K; k0 += 64) {
        #pragma unroll
        for (int i = 0; i < 4; ++i) {
            const int j = wave * 4 + i;
            load_lds16(A  + (size_t)(m0 + 8 * j + srow) * K + k0 + sgr * 8,
                       &As[8 * j * 64]);
            load_lds16(Bt + (size_t)(n0 + 8 * j + srow) * K + k0 + sgr * 8,
                       &Bs[8 * j * 64]);
        }
        __syncthreads();

        #pragma unroll
        for (int kt = 0; kt < 2; ++kt) {
            bf16x8 af[4], bf[4];
            #pragma unroll
            for (int i = 0; i < 4; ++i) {
                af[i] = *(const bf16x8*)&As[(mw + i * 16 + l15) * 64
                                            + (((kt * 4 + quad) ^ swz) * 8)];
                bf[i] = *(const bf16x8*)&Bs[(nw + i * 16 + l15) * 64
                                            + (((kt * 4 + quad) ^ swz) * 8)];
            }
            #pragma unroll
            for (int mt = 0; mt < 4; ++mt)
                #pragma unroll
                for (int nt = 0; nt < 4; ++nt)
                    acc[mt][nt] = __builtin_amdgcn_mfma_f32_16x16x32_bf16(
                        af[mt], bf[nt], acc[mt][nt], 0, 0, 0);
        }
        __syncthreads();
    }

    if (cmode == 2) {
        ushort_t* Vt = (ushort_t*)Cv;
        #pragma unroll
        for (int mt = 0; mt < 4; ++mt)
            #pragma unroll
            for (int nt = 0; nt < 4; ++nt) {
                int col  = n0 + nw + nt * 16 + l15;
                int row0 = m0 + mw + mt * 16 + quad * 4;
                ushort_t pk[4] = {f2bf(acc[mt][nt][0]), f2bf(acc[mt][nt][1]),
                                  f2bf(acc[mt][nt][2]), f2bf(acc[mt][nt][3])};
                *(uint2*)&Vt[(size_t)col * L_SEQ + row0] = *(const uint2*)pk;
            }
        return;
    }

    const int odd = lane & 1;
    #pragma unroll
    for (int mtp = 0; mtp < 2; ++mtp)
        #pragma unroll
        for (int nt = 0; nt < 4; ++nt)
            #pragma unroll
            for (int r = 0; r < 4; ++r) {
                float zA = acc[2 * mtp][nt][r];
                float zB = acc[2 * mtp + 1][nt][r];
                float send = odd ? zA : zB;
                float got  = __shfl_xor(send, 1);
                const int row = m0 + mw + (2 * mtp + odd) * 16 + quad * 4 + r;
                const int col = n0 + nw + nt * 16 + (l15 & ~1);
                if (cmode == 1) {
                    float2 w2 = odd ? make_float2(got, zB) : make_float2(zA, got);
                    *(float2*)((float*)Cv + (size_t)row * NOUT + col) = w2;
                } else {
                    float lo = odd ? got : zA;
                    float hi = odd ? zB  : got;
                    unsigned w = cvt_pk_bf16(lo, hi);
                    *(unsigned*)((ushort_t*)Cv + (size_t)row * NOUT + col) = w;
                }
            }
}

// qkv: 768 blocks, z-innermost decode (verified R6).
__global__ __launch_bounds__(256) void qkv128(const ushort_t* __restrict__ xb,
                                              const ushort_t* __restrict__ wT,
                                              ushort_t* Qp, ushort_t* Kp, ushort_t* Vt) {
    const int b = blockIdx.x;
    const int n0 = (b & 7) * 128;
    const int u  = b >> 3;
    const int m0 = (u / 3) * 128;
    const int z  = u % 3;
    const ushort_t* Bt = wT + (size_t)z * (DM * DM);
    if (z == 0)      gemm128_body(xb, Bt, Qp, 0, m0, n0);
    else if (z == 1) gemm128_body(xb, Bt, Kp, 0, m0, n0);
    else             gemm128_body(xb, Bt, Vt, 2, m0, n0);
}

__global__ __launch_bounds__(256) void ogemm128(const void* __restrict__ xdet,
                                                const ushort_t* __restrict__ An,
                                                const ushort_t* __restrict__ woT,
                                                void* __restrict__ C) {
    bool f32 = detect_f32((const ushort_t*)xdet);
    const int b = blockIdx.x;
    const int n0 = (b & 7) * 128, m0 = (b >> 3) * 128;
    gemm128_body(An, woT, C, f32 ? 1 : 0, m0, n0);
}

// ---------------------------------------------------------------------------
// Flash attention — R11 verified (89-91 us). FALLBACK (small workspace).
// ---------------------------------------------------------------------------
__global__ __launch_bounds__(512) void attn_kernel(const ushort_t* __restrict__ Q,
                                                   const ushort_t* __restrict__ Kp,
                                                   const ushort_t* __restrict__ Vt,
                                                   ushort_t* __restrict__ O) {
    __shared__ ushort_t Ks[2][128 * 64];
    __shared__ ushort_t Vs[2][64 * 128];
    __shared__ ushort_t Pt[128 * 128];

    const int b    = blockIdx.x;
    const int h    = 2 * (b & 7) + ((b >> 3) & 1);
    const int px   = b >> 4;
    const int t    = threadIdx.x;
    const int lane = t & 63, wave = t >> 6;
    const int l15  = lane & 15, quad = lane >> 4;
    const float LOG2E  = 1.44269504f;
    const float slope2 = exp2f(-0.5f * (float)(h + 1)) * LOG2E;
    const float c0     = 0.125f * LOG2E;
    const float qd4f   = (float)(quad * 4);

    const int krow = lane >> 3, kgr = (lane & 7) ^ (lane >> 3);
    const int vsub = lane >> 4;
    const int swz = l15 & 7;

    auto stage_load = [&](int buf, int kv0) {
        #pragma unroll
        for (int i = 0; i < 2; ++i) {
            const int j = wave * 2 + i;
            load_lds16(Kp + (size_t)(kv0 + 8 * j + krow) * DM + h * HD + kgr * 8,
                       &Ks[buf][8 * j * 64]);
        }
        #pragma unroll
        for (int i = 0; i < 2; ++i) {
            const int j = wave * 2 + i;
            const int d = 4 * j + vsub;
            const int g = (lane & 15) ^ (4 * (j & 1) + vsub);
            load_lds16(Vt + (size_t)(h * HD + d) * L_SEQ + kv0 + g * 8,
                       &Vs[buf][4 * j * 128]);
        }
    };

    int par = 0;
    stage_load(0, 0);

    #pragma unroll
    for (int half = 0; half < 2; ++half) {
        const int qb = half ? px : (31 - px);
        const int q0 = qb * 128;
        const int qg = q0 + wave * 16 + l15;
        const float qf = (float)qg;
        const int nst = half ? (px + 1) : (32 - px);

        bf16x8 bq[2];
        #pragma unroll
        for (int kt = 0; kt < 2; ++kt)
            bq[kt] = *(const bf16x8*)(Q + (size_t)qg * DM + h * HD + kt * 32 + quad * 8);

        f32x4 acc_o[4] = {};
        float l_r = 0.f;

        for (int s = 0; s < nst; ++s) {
            const int kv0 = s * 128;
            __syncthreads();

            const int nkv0 = (s + 1 < nst) ? (s + 1) * 128 : 0;
            stage_load(par ^ 1, nkv0);

            f32x4 sacc[8];
            #pragma unroll
            for (int mt = 0; mt < 8; ++mt) sacc[mt] = (f32x4){0.f, 0.f, 0.f, 0.f};
            __builtin_amdgcn_s_setprio(1);
            #pragma unroll
            for (int kt = 0; kt < 2; ++kt)
                #pragma unroll
                for (int mt = 0; mt < 8; ++mt) {
                    bf16x8 a = *(const bf16x8*)&Ks[par][(mt * 16 + l15) * 64
                                                        + (((kt * 4 + quad) ^ swz) * 8)];
                    sacc[mt] = __builtin_amdgcn_mfma_f32_16x16x32_bf16(a, bq[kt], sacc[mt], 0, 0, 0);
                }
            __builtin_amdgcn_s_setprio(0);

            const bool diag = (kv0 + 128 > q0);
            const float off = slope2 * ((float)kv0 + qd4f - qf);
            float rs = 0.f;
            #pragma unroll
            for (int mt = 0; mt < 8; ++mt)
                #pragma unroll
                for (int r = 0; r < 4; ++r) {
                    float kvl = (float)(mt * 16 + r);
                    float s2  = fmaf(sacc[mt][r], c0, fmaf(slope2, kvl, off));
                    if (diag) {
                        int kvg = kv0 + mt * 16 + quad * 4 + r;
                        s2 = (kvg <= qg) ? s2 : -1e30f;
                    }
                    float p = ex2(s2);
                    sacc[mt][r] = p;
                    rs += p;
                }
            rs += __shfl_xor(rs, 16);
            rs += __shfl_xor(rs, 32);
            l_r += rs;

            #pragma unroll
            for (int mt = 0; mt < 8; ++mt) {
                union { float f; unsigned u; } a0, a1, a2, a3;
                a0.f = sacc[mt][0]; a1.f = sacc[mt][1];
                a2.f = sacc[mt][2]; a3.f = sacc[mt][3];
                uint2 w;
                w.x = __builtin_amdgcn_perm(a1.u, a0.u, 0x07060302);
                w.y = __builtin_amdgcn_perm(a3.u, a2.u, 0x07060302);
                const int g = mt * 2 + (quad >> 1);
                *(uint2*)&Pt[(wave * 16 + l15) * 128
                             + ((g ^ swz) * 8 + (quad & 1) * 4)] = w;
            }
            __threadfence_block();

            __builtin_amdgcn_s_setprio(1);
            #pragma unroll
            for (int kt = 0; kt < 4; ++kt) {
                bf16x8 a = *(const bf16x8*)&Pt[(wave * 16 + l15) * 128
                                               + (((kt * 4 + quad) ^ swz) * 8)];
                #pragma unroll
                for (int nt = 0; nt < 4; ++nt) {
                    bf16x8 bvv = *(const bf16x8*)&Vs[par][(nt * 16 + l15) * 128
                                                          + (((kt * 4 + quad) ^ swz) * 8)];
                    acc_o[nt] = __builtin_amdgcn_mfma_f32_16x16x32_bf16(a, bvv, acc_o[nt], 0, 0, 0);
                }
            }
            __builtin_amdgcn_s_setprio(0);

            par ^= 1;
        }

        float linv[4];
        #pragma unroll
        for (int r = 0; r < 4; ++r) linv[r] = 1.0f / __shfl(l_r, quad * 4 + r);
        #pragma unroll
        for (int nt = 0; nt < 4; ++nt)
            #pragma unroll
            for (int r = 0; r < 4; ++r) {
                int row = q0 + wave * 16 + quad * 4 + r;
                O[(size_t)row * DM + h * HD + nt * 16 + l15] = f2bf(acc_o[nt][r] * linv[r]);
            }
    }
}

// ---------------------------------------------------------------------------
// R15 attn 2-way SPLIT (verified 70 us). MID-TIER fallback (72.5 MB ws).
// ---------------------------------------------------------------------------
__global__ __launch_bounds__(512, 4) void attn_split(const ushort_t* __restrict__ Q,
                                                     const ushort_t* __restrict__ Kp,
                                                     const ushort_t* __restrict__ Vt,
                                                     float* __restrict__ Op,
                                                     float* __restrict__ Lp) {
    __shared__ ushort_t Ks[128 * 64];
    __shared__ ushort_t Vs[64 * 128];
    __shared__ ushort_t Pt[128 * 128];

    const int b    = blockIdx.x;
    const int bb   = b & 255;
    const int v    = b >> 8;
    const int h    = 2 * (bb & 7) + ((bb >> 3) & 1);
    const int px   = bb >> 4;
    const int t    = threadIdx.x;
    const int lane = t & 63, wave = t >> 6;
    const int l15  = lane & 15, quad = lane >> 4;
    const float LOG2E  = 1.44269504f;
    const float slope2 = exp2f(-0.5f * (float)(h + 1)) * LOG2E;
    const float c0     = 0.125f * LOG2E;
    const float qd4f   = (float)(quad * 4);

    const int krow = lane >> 3, kgr = (lane & 7) ^ (lane >> 3);
    const int vsub = lane >> 4;
    const int swz = l15 & 7;

    float* Opv = Op + (size_t)v * L_SEQ * DM;

    auto stage_load = [&](int kv0) {
        #pragma unroll
        for (int i = 0; i < 2; ++i) {
            const int j = wave * 2 + i;
            load_lds16(Kp + (size_t)(kv0 + 8 * j + krow) * DM + h * HD + kgr * 8,
                       &Ks[8 * j * 64]);
        }
        #pragma unroll
        for (int i = 0; i < 2; ++i) {
            const int j = wave * 2 + i;
            const int d = 4 * j + vsub;
            const int g = (lane & 15) ^ (4 * (j & 1) + vsub);
            load_lds16(Vt + (size_t)(h * HD + d) * L_SEQ + kv0 + g * 8,
                       &Vs[4 * j * 128]);
        }
    };

    #pragma unroll
    for (int half = 0; half < 2; ++half) {
        const int qb = half ? px : (31 - px);
        const int q0 = qb * 128;
        const int qg = q0 + wave * 16 + l15;
        const float qf = (float)qg;
        const int nst = half ? (px + 1) : (32 - px);

        bf16x8 bq[2];
        #pragma unroll
        for (int kt = 0; kt < 2; ++kt)
            bq[kt] = *(const bf16x8*)(Q + (size_t)qg * DM + h * HD + kt * 32 + quad * 8);

        f32x4 acc_o[4] = {};
        float l_r = 0.f;

        for (int s = v; s < nst; s += 2) {
            const int kv0 = s * 128;
            stage_load(kv0);
            __syncthreads();

            f32x4 sacc[8];
            #pragma unroll
            for (int mt = 0; mt < 8; ++mt) sacc[mt] = (f32x4){0.f, 0.f, 0.f, 0.f};
            __builtin_amdgcn_s_setprio(1);
            #pragma unroll
            for (int kt = 0; kt < 2; ++kt)
                #pragma unroll
                for (int mt = 0; mt < 8; ++mt) {
                    bf16x8 a = *(const bf16x8*)&Ks[(mt * 16 + l15) * 64
                                                   + (((kt * 4 + quad) ^ swz) * 8)];
                    sacc[mt] = __builtin_amdgcn_mfma_f32_16x16x32_bf16(a, bq[kt], sacc[mt], 0, 0, 0);
                }
            __builtin_amdgcn_s_setprio(0);

            const bool diag = (kv0 + 128 > q0);
            const float off = slope2 * ((float)kv0 + qd4f - qf);
            float rs = 0.f;
            #pragma unroll
            for (int mt = 0; mt < 8; ++mt)
                #pragma unroll
                for (int r = 0; r < 4; ++r) {
                    float kvl = (float)(mt * 16 + r);
                    float s2  = fmaf(sacc[mt][r], c0, fmaf(slope2, kvl, off));
                    if (diag) {
                        int kvg = kv0 + mt * 16 + quad * 4 + r;
                        s2 = (kvg <= qg) ? s2 : -1e30f;
                    }
                    float p = ex2(s2);
                    sacc[mt][r] = p;
                    rs += p;
                }
            rs += __shfl_xor(rs, 16);
            rs += __shfl_xor(rs, 32);
            l_r += rs;

            #pragma unroll
            for (int mt = 0; mt < 8; ++mt) {
                union { float f; unsigned u; } a0, a1, a2, a3;
                a0.f = sacc[mt][0]; a1.f = sacc[mt][1];
                a2.f = sacc[mt][2]; a3.f = sacc[mt][3];
                uint2 w;
                w.x = __builtin_amdgcn_perm(a1.u, a0.u, 0x07060302);
                w.y = __builtin_amdgcn_perm(a3.u, a2.u, 0x07060302);
                const int g = mt * 2 + (quad >> 1);
                *(uint2*)&Pt[(wave * 16 + l15) * 128
                             + ((g ^ swz) * 8 + (quad & 1) * 4)] = w;
            }
            __threadfence_block();

            __builtin_amdgcn_s_setprio(1);
            #pragma unroll
            for (int kt = 0; kt < 4; ++kt) {
                bf16x8 a = *(const bf16x8*)&Pt[(wave * 16 + l15) * 128
                                               + (((kt * 4 + quad) ^ swz) * 8)];
                #pragma unroll
                for (int nt = 0; nt < 4; ++nt) {
                    bf16x8 bvv = *(const bf16x8*)&Vs[(nt * 16 + l15) * 128
                                                     + (((kt * 4 + quad) ^ swz) * 8)];
                    acc_o[nt] = __builtin_amdgcn_mfma_f32_16x16x32_bf16(a, bvv, acc_o[nt], 0, 0, 0);
                }
            }
            __builtin_amdgcn_s_setprio(0);

            __syncthreads();
        }

        #pragma unroll
        for (int nt = 0; nt < 4; ++nt)
            #pragma unroll
            for (int r = 0; r < 4; ++r) {
                int row = q0 + wave * 16 + quad * 4 + r;
                Opv[(size_t)row * DM + h * HD + nt * 16 + l15] = acc_o[nt][r];
            }
        if (quad == 0)
            Lp[(size_t)v * (NH * L_SEQ) + (size_t)h * L_SEQ + qg] = l_r;
    }
}

__global__ __launch_bounds__(256) void attn_combine(const float* __restrict__ Op,
                                                    const float* __restrict__ Lp,
                                                    ushort_t* __restrict__ An) {
    const int i = (blockIdx.x * 256 + threadIdx.x) * 8;
    const int row = i >> 10;
    const int h   = (i & 1023) >> 6;
    const float l0 = Lp[(size_t)h * L_SEQ + row];
    const float l1 = Lp[(size_t)NH * L_SEQ + (size_t)h * L_SEQ + row];
    const float linv = 1.0f / (l0 + l1);
    const size_t V1 = (size_t)L_SEQ * DM;
    float4 a0 = *(const float4*)(Op + i);
    float4 a1 = *(const float4*)(Op + i + 4);
    float4 b0 = *(const float4*)(Op + V1 + i);
    float4 b1 = *(const float4*)(Op + V1 + i + 4);
    uint4 u;
    u.x = cvt_pk_bf16((a0.x + b0.x) * linv, (a0.y + b0.y) * linv);
    u.y = cvt_pk_bf16((a0.z + b0.z) * linv, (a0.w + b0.w) * linv);
    u.z = cvt_pk_bf16((a1.x + b1.x) * linv, (a1.y + b1.y) * linv);
    u.w = cvt_pk_bf16((a1.z + b1.z) * linv, (a1.w + b1.w) * linv);
    *(uint4*)(An + i) = u;
}

// ---------------------------------------------------------------------------
// R17 attn 3-way SPLIT: KVBLK=128 (no tiny-tile overhead), Pt halved to
// 128x64 via two-half PV (Pt rows are WAVE-PRIVATE -> no extra barrier,
// just a fence per half; half-Pt index math = split4's passed code, Vs
// reads = split2's verified kt 0..3). LDS = Ks 16K + Vs 16K + Pt 16K =
// 48 KB -> 3 blocks/CU; grid 768 = 16h x 16px x 3 parity = exactly 3/CU,
// round-robin puts all 3 parities of one (h,px) on the same CU (shared K/V
// in L2, identical durations). Partials 3x16 MB (split2's regime, not
// split4's 64 MB + evictions).
// ---------------------------------------------------------------------------
__global__ __launch_bounds__(512, 6) void attn_split3(const ushort_t* __restrict__ Q,
                                                      const ushort_t* __restrict__ Kp,
                                                      const ushort_t* __restrict__ Vt,
                                                      float* __restrict__ Op,
                                                      float* __restrict__ Lp) {
    __shared__ ushort_t Ks[128 * 64];   // [kv][d], swizzled, 16 KB
    __shared__ ushort_t Vs[64 * 128];   // [d][kv], swizzled, 16 KB
    __shared__ ushort_t Pt[128 * 64];   // [q][kv-half], swizzled, 16 KB

    const int b    = blockIdx.x;               // 0..767
    const int bb   = b & 255;
    const int v    = b >> 8;                   // kv parity 0..2
    const int h    = 2 * (bb & 7) + ((bb >> 3) & 1);
    const int px   = bb >> 4;
    const int t    = threadIdx.x;
    const int lane = t & 63, wave = t >> 6;
    const int l15  = lane & 15, quad = lane >> 4;
    const float LOG2E  = 1.44269504f;
    const float slope2 = exp2f(-0.5f * (float)(h + 1)) * LOG2E;
    const float c0     = 0.125f * LOG2E;
    const float qd4f   = (float)(quad * 4);

    const int krow = lane >> 3, kgr = (lane & 7) ^ (lane >> 3);
    const int vsub = lane >> 4;
    const int swz = l15 & 7;

    float* Opv = Op + (size_t)v * L_SEQ * DM;

    auto stage_load = [&](int kv0) {
        #pragma unroll
        for (int i = 0; i < 2; ++i) {
            const int j = wave * 2 + i;
            load_lds16(Kp + (size_t)(kv0 + 8 * j + krow) * DM + h * HD + kgr * 8,
                       &Ks[8 * j * 64]);
        }
        #pragma unroll
        for (int i = 0; i < 2; ++i) {
            const int j = wave * 2 + i;
            const int d = 4 * j + vsub;
            const int g = (lane & 15) ^ (4 * (j & 1) + vsub);
            load_lds16(Vt + (size_t)(h * HD + d) * L_SEQ + kv0 + g * 8,
                       &Vs[4 * j * 128]);
        }
    };

    #pragma unroll
    for (int half = 0; half < 2; ++half) {
        const int qb = half ? px : (31 - px);
        const int q0 = qb * 128;
        const int qg = q0 + wave * 16 + l15;
        const float qf = (float)qg;
        const int nst = half ? (px + 1) : (32 - px);

        bf16x8 bq[2];
        #pragma unroll
        for (int kt = 0; kt < 2; ++kt)
            bq[kt] = *(const bf16x8*)(Q + (size_t)qg * DM + h * HD + kt * 32 + quad * 8);

        f32x4 acc_o[4] = {};
        float l_r = 0.f;

        for (int s = v; s < nst; s += 3) {
            const int kv0 = s * 128;
            stage_load(kv0);
            __syncthreads();                  // glds drained; prev compute done

            f32x4 sacc[8];
            #pragma unroll
            for (int mt = 0; mt < 8; ++mt) sacc[mt] = (f32x4){0.f, 0.f, 0.f, 0.f};
            __builtin_amdgcn_s_setprio(1);
            #pragma unroll
            for (int kt = 0; kt < 2; ++kt)
                #pragma unroll
                for (int mt = 0; mt < 8; ++mt) {
                    bf16x8 a = *(const bf16x8*)&Ks[(mt * 16 + l15) * 64
                                                   + (((kt * 4 + quad) ^ swz) * 8)];
                    sacc[mt] = __builtin_amdgcn_mfma_f32_16x16x32_bf16(a, bq[kt], sacc[mt], 0, 0, 0);
                }
            __builtin_amdgcn_s_setprio(0);

            const bool diag = (kv0 + 128 > q0);
            const float off = slope2 * ((float)kv0 + qd4f - qf);
            float rs = 0.f;
            #pragma unroll
            for (int mt = 0; mt < 8; ++mt)
                #pragma unroll
                for (int r = 0; r < 4; ++r) {
                    float kvl = (float)(mt * 16 + r);
                    float s2  = fmaf(sacc[mt][r], c0, fmaf(slope2, kvl, off));
                    if (diag) {
                        int kvg = kv0 + mt * 16 + quad * 4 + r;
                        s2 = (kvg <= qg) ? s2 : -1e30f;
                    }
                    float p = ex2(s2);          // fixed-base softmax
                    sacc[mt][r] = p;
                    rs += p;
                }
            rs += __shfl_xor(rs, 16);
            rs += __shfl_xor(rs, 32);
            l_r += rs;

            // PV in two kv-halves through the 16 KB Pt (wave-private rows:
            // no barrier between halves, only a fence for write->read order).
            #pragma unroll
            for (int h2 = 0; h2 < 2; ++h2) {
                #pragma unroll
                for (int mtl = 0; mtl < 4; ++mtl) {
                    const int mt = h2 * 4 + mtl;
                    union { float f; unsigned u; } a0, a1, a2, a3;
                    a0.f = sacc[mt][0]; a1.f = sacc[mt][1];
                    a2.f = sacc[mt][2]; a3.f = sacc[mt][3];
                    uint2 w;
                    w.x = __builtin_amdgcn_perm(a1.u, a0.u, 0x07060302);
                    w.y = __builtin_amdgcn_perm(a3.u, a2.u, 0x07060302);
                    const int g = mtl * 2 + (quad >> 1);   // octet 0..7 in half
                    *(uint2*)&Pt[(wave * 16 + l15) * 64
                                 + ((g ^ swz) * 8 + (quad & 1) * 4)] = w;
                }
                __threadfence_block();

                __builtin_amdgcn_s_setprio(1);
                #pragma unroll
                for (int kt = 0; kt < 2; ++kt) {
                    bf16x8 a = *(const bf16x8*)&Pt[(wave * 16 + l15) * 64
                                                   + (((kt * 4 + quad) ^ swz) * 8)];
                    const int ktg = h2 * 2 + kt;           // global kv octet grp
                    #pragma unroll
                    for (int nt = 0; nt < 4; ++nt) {
                        bf16x8 bvv = *(const bf16x8*)&Vs[(nt * 16 + l15) * 128
                                                         + (((ktg * 4 + quad) ^ swz) * 8)];
                        acc_o[nt] = __builtin_amdgcn_mfma_f32_16x16x32_bf16(a, bvv, acc_o[nt], 0, 0, 0);
                    }
                }
                __builtin_amdgcn_s_setprio(0);
            }

            __syncthreads();                  // all waves done before next stage
        }

        // partial epilogue: UNNORMALIZED f32 O + row-sum l
        #pragma unroll
        for (int nt = 0; nt < 4; ++nt)
            #pragma unroll
            for (int r = 0; r < 4; ++r) {
                int row = q0 + wave * 16 + quad * 4 + r;
                Opv[(size_t)row * DM + h * HD + nt * 16 + l15] = acc_o[nt][r];
            }
        if (quad == 0)
            Lp[(size_t)v * (NH * L_SEQ) + (size_t)h * L_SEQ + qg] = l_r;
    }
}

// combine3: An = (O0+O1+O2) / (l0+l1+l2), bf16. 2048 x 256 x 8 elems.
__global__ __launch_bounds__(256) void attn_combine3(const float* __restrict__ Op,
                                                     const float* __restrict__ Lp,
                                                     ushort_t* __restrict__ An) {
    const int i = (blockIdx.x * 256 + threadIdx.x) * 8;
    const int row = i >> 10;
    const int h   = (i & 1023) >> 6;
    float l = 0.f;
    #pragma unroll
    for (int v = 0; v < 3; ++v)
        l += Lp[(size_t)v * (NH * L_SEQ) + (size_t)h * L_SEQ + row];
    const float linv = 1.0f / l;
    const size_t V1 = (size_t)L_SEQ * DM;
    float4 s0 = {0, 0, 0, 0}, s1 = {0, 0, 0, 0};
    #pragma unroll
    for (int v = 0; v < 3; ++v) {
        float4 a0 = *(const float4*)(Op + (size_t)v * V1 + i);
        float4 a1 = *(const float4*)(Op + (size_t)v * V1 + i + 4);
        s0.x += a0.x; s0.y += a0.y; s0.z += a0.z; s0.w += a0.w;
        s1.x += a1.x; s1.y += a1.y; s1.z += a1.z; s1.w += a1.w;
    }
    uint4 u;
    u.x = cvt_pk_bf16(s0.x * linv, s0.y * linv);
    u.y = cvt_pk_bf16(s0.z * linv, s0.w * linv);
    u.z = cvt_pk_bf16(s1.x * linv, s1.y * linv);
    u.w = cvt_pk_bf16(s1.z * linv, s1.w * linv);
    *(uint4*)(An + i) = u;
}

// ---------------------------------------------------------------------------
extern "C" void kernel_launch(void* const* d_in, const int* in_sizes, int n_in,
                              void* d_out, int out_size, void* d_ws, size_t ws_size,
                              hipStream_t stream) {
    const void* x  = d_in[0];
    const void* wq = d_in[1];
    const void* wk = d_in[2];
    const void* wv = d_in[3];
    const void* wo = d_in[4];

    const size_t SZ = (size_t)L_SEQ * DM;   // 4M elems
    const size_t WZ = (size_t)DM * DM;      // 1M elems
    ushort_t* xb = (ushort_t*)d_ws;         // 8 MB
    ushort_t* wT = xb + SZ;                 // 4 x 2 MB
    ushort_t* Qp = wT + 4 * WZ;             // 8 MB
    ushort_t* Kp = Qp + SZ;                 // 8 MB
    ushort_t* Vt = Kp + SZ;                 // 8 MB  -> 40 MB so far
    ushort_t* An = xb;                      // xb dead after qkv -> safe alias

    float* Op = (float*)(Vt + SZ);          // up to 3 x 16 MB partial O (f32)
    float* Lp3 = Op + 3 * SZ;               // 3 x 256 KB partial l
    float* Lp2 = Op + 2 * SZ;               // (2-way layout)
    const size_t base  = 40ull * 1024 * 1024;
    const size_t need3 = base + 3 * SZ * 4 + 3ull * NH * L_SEQ * 4;
    const size_t need2 = base + 2 * SZ * 4 + 2ull * NH * L_SEQ * 4;

    convert_all<<<dim3(16, 16, 5), 256, 0, stream>>>(x, wq, wk, wv, wo, xb, wT);
    qkv128<<<768, 256, 0, stream>>>(xb, wT, Qp, Kp, Vt);
    if (ws_size >= need3) {
        attn_split3<<<768, 512, 0, stream>>>(Qp, Kp, Vt, Op, Lp3);
        attn_combine3<<<2048, 256, 0, stream>>>(Op, Lp3, An);
    } else if (ws_size >= need2) {
        attn_split<<<512, 512, 0, stream>>>(Qp, Kp, Vt, Op, Lp2);
        attn_combine<<<2048, 256, 0, stream>>>(Op, Lp2, An);
    } else {
        attn_kernel<<<256, 512, 0, stream>>>(Qp, Kp, Vt, An);
    }
    ogemm128<<<256, 256, 0, stream>>>(x, An, wT + 3 * WZ, d_out);
}

// Round 18
// 221.988 us; speedup vs baseline: 1.2160x; 1.2160x over previous
//
#include <hip/hip_runtime.h>

#define L_SEQ 4096
#define DM    1024
#define NH    16
#define HD    64

typedef unsigned short ushort_t;
typedef __attribute__((ext_vector_type(8))) short bf16x8;
typedef __attribute__((ext_vector_type(4))) float f32x4;

__device__ inline unsigned short f2bf(float f) {
    union { float f; unsigned int u; } v; v.f = f;
    unsigned int r = v.u + 0x7fffu + ((v.u >> 16) & 1u);
    return (unsigned short)(r >> 16);
}

// pack two f32 -> two bf16 (RNE) in one instruction
__device__ inline unsigned cvt_pk_bf16(float lo, float hi) {
    unsigned w;
    asm("v_cvt_pk_bf16_f32 %0, %1, %2" : "=v"(w) : "v"(lo), "v"(hi));
    return w;
}

// raw v_exp_f32 (2^x); exact enough for our domain (args <= ~40; -1e30 -> 0)
__device__ inline float ex2(float x) {
#if __has_builtin(__builtin_amdgcn_exp2f)
    return __builtin_amdgcn_exp2f(x);
#else
    return exp2f(x);
#endif
}

// async global->LDS, 16B/lane. LDS dest = wave-uniform base + lane*16.
__device__ inline void load_lds16(const ushort_t* g, ushort_t* l) {
    __builtin_amdgcn_global_load_lds(
        (const __attribute__((address_space(1))) unsigned int*)g,
        (__attribute__((address_space(3))) unsigned int*)l, 16, 0, 0);
}

// ---------------------------------------------------------------------------
// Runtime input-dtype detection (bf16 vs fp32 global buffers). Verified R3.
// ---------------------------------------------------------------------------
__device__ inline bool detect_f32(const ushort_t* xraw) {
    __shared__ int s_flag;
    const int t = threadIdx.x;
    if (t < 64) {
        unsigned e = (xraw[2 * t] >> 7) & 0xFFu;
        unsigned long long m = __ballot(e >= 0x88u);
        if (t == 0) s_flag = (__popcll(m) >= 8) ? 1 : 0;
    }
    __syncthreads();
    return s_flag != 0;
}

// ---------------------------------------------------------------------------
// Fused converts: z=0..3 -> weight z transposed bf16 wT[n][k]; z=4 -> x bf16.
// grid (16,16,5) x 256 thr.
// ---------------------------------------------------------------------------
__global__ __launch_bounds__(256) void convert_all(const void* __restrict__ xv,
                                                   const void* __restrict__ w0,
                                                   const void* __restrict__ w1,
                                                   const void* __restrict__ w2,
                                                   const void* __restrict__ w3,
                                                   ushort_t* __restrict__ xb,
                                                   ushort_t* __restrict__ wT) {
    bool f32 = detect_f32((const ushort_t*)xv);
    const int z = blockIdx.z;
    const int t = threadIdx.x;

    if (z == 4) {
        const int B0 = (blockIdx.y * 16 + blockIdx.x) * 16384;
        #pragma unroll
        for (int it = 0; it < 8; ++it) {
            const int i = B0 + it * 2048 + t * 8;
            if (f32) {
                const float* xf = (const float*)xv;
                float4 v0 = *(const float4*)(xf + i);
                float4 v1 = *(const float4*)(xf + i + 4);
                uint4 u;
                u.x = cvt_pk_bf16(v0.x, v0.y);
                u.y = cvt_pk_bf16(v0.z, v0.w);
                u.z = cvt_pk_bf16(v1.x, v1.y);
                u.w = cvt_pk_bf16(v1.z, v1.w);
                *(uint4*)(xb + i) = u;
            } else {
                *(uint4*)(xb + i) = *(const uint4*)((const ushort_t*)xv + i);
            }
        }
        return;
    }

    const void* w = (z == 0) ? w0 : (z == 1) ? w1 : (z == 2) ? w2 : w3;
    ushort_t* out = wT + (size_t)z * (DM * DM);
    __shared__ ushort_t T[64][65];
    const int k0 = blockIdx.x * 64, n0 = blockIdx.y * 64;
    #pragma unroll
    for (int i = 0; i < 16; ++i) {
        int e = t + i * 256;
        int r = e >> 6, c = e & 63;
        T[r][c] = f32 ? f2bf(((const float*)w)[(size_t)(k0 + r) * DM + n0 + c])
                      : ((const ushort_t*)w)[(size_t)(k0 + r) * DM + n0 + c];
    }
    __syncthreads();
    #pragma unroll
    for (int i = 0; i < 16; ++i) {
        int e = t + i * 256;
        int d = e >> 6, l = e & 63;
        out[(size_t)(n0 + d) * DM + k0 + l] = T[l][d];
    }
}

// ---------------------------------------------------------------------------
// R11 GEMM (verified best): BK=64, single-buffered, 128x128 tile.
// cmode: 0 bf16 row-major, 1 f32 row-major, 2 bf16 transposed (Vt[d][L]).
// ---------------------------------------------------------------------------
__device__ inline void gemm128_body(const ushort_t* __restrict__ A,
                                    const ushort_t* __restrict__ Bt,
                                    void* __restrict__ Cv, int cmode,
                                    int m0, int n0) {
    constexpr int K = 1024, NOUT = 1024;
    __shared__ ushort_t As[128 * 64];   // [r][k], swizzled, 16 KB
    __shared__ ushort_t Bs[128 * 64];

    const int t = threadIdx.x, lane = t & 63, wave = t >> 6;
    const int l15 = lane & 15, quad = lane >> 4;
    const int mw = (wave >> 1) * 64, nw = (wave & 1) * 64;
    const int srow = lane >> 3;
    const int sgr  = (lane & 7) ^ (lane >> 3);
    const int swz  = l15 & 7;

    f32x4 acc[4][4] = {};

    for (int k0 = 0; k0 < K; k0 += 64) {
        #pragma unroll
        for (int i = 0; i < 4; ++i) {
            const int j = wave * 4 + i;
            load_lds16(A  + (size_t)(m0 + 8 * j + srow) * K + k0 + sgr * 8,
                       &As[8 * j * 64]);
            load_lds16(Bt + (size_t)(n0 + 8 * j + srow) * K + k0 + sgr * 8,
                       &Bs[8 * j * 64]);
        }
        __syncthreads();

        #pragma unroll
        for (int kt = 0; kt < 2; ++kt) {
            bf16x8 af[4], bf[4];
            #pragma unroll
            for (int i = 0; i < 4; ++i) {
                af[i] = *(const bf16x8*)&As[(mw + i * 16 + l15) * 64
                                            + (((kt * 4 + quad) ^ swz) * 8)];
                bf[i] = *(const bf16x8*)&Bs[(nw + i * 16 + l15) * 64
                                            + (((kt * 4 + quad) ^ swz) * 8)];
            }
            #pragma unroll
            for (int mt = 0; mt < 4; ++mt)
                #pragma unroll
                for (int nt = 0; nt < 4; ++nt)
                    acc[mt][nt] = __builtin_amdgcn_mfma_f32_16x16x32_bf16(
                        af[mt], bf[nt], acc[mt][nt], 0, 0, 0);
        }
        __syncthreads();
    }

    if (cmode == 2) {
        ushort_t* Vt = (ushort_t*)Cv;
        #pragma unroll
        for (int mt = 0; mt < 4; ++mt)
            #pragma unroll
            for (int nt = 0; nt < 4; ++nt) {
                int col  = n0 + nw + nt * 16 + l15;
                int row0 = m0 + mw + mt * 16 + quad * 4;
                ushort_t pk[4] = {f2bf(acc[mt][nt][0]), f2bf(acc[mt][nt][1]),
                                  f2bf(acc[mt][nt][2]), f2bf(acc[mt][nt][3])};
                *(uint2*)&Vt[(size_t)col * L_SEQ + row0] = *(const uint2*)pk;
            }
        return;
    }

    const int odd = lane & 1;
    #pragma unroll
    for (int mtp = 0; mtp < 2; ++mtp)
        #pragma unroll
        for (int nt = 0; nt < 4; ++nt)
            #pragma unroll
            for (int r = 0; r < 4; ++r) {
                float zA = acc[2 * mtp][nt][r];
                float zB = acc[2 * mtp + 1][nt][r];
                float send = odd ? zA : zB;
                float got  = __shfl_xor(send, 1);
                const int row = m0 + mw + (2 * mtp + odd) * 16 + quad * 4 + r;
                const int col = n0 + nw + nt * 16 + (l15 & ~1);
                if (cmode == 1) {
                    float2 w2 = odd ? make_float2(got, zB) : make_float2(zA, got);
                    *(float2*)((float*)Cv + (size_t)row * NOUT + col) = w2;
                } else {
                    float lo = odd ? got : zA;
                    float hi = odd ? zB  : got;
                    unsigned w = cvt_pk_bf16(lo, hi);
                    *(unsigned*)((ushort_t*)Cv + (size_t)row * NOUT + col) = w;
                }
            }
}

// qkv: 768 blocks, z-innermost decode (verified R6).
__global__ __launch_bounds__(256) void qkv128(const ushort_t* __restrict__ xb,
                                              const ushort_t* __restrict__ wT,
                                              ushort_t* Qp, ushort_t* Kp, ushort_t* Vt) {
    const int b = blockIdx.x;
    const int n0 = (b & 7) * 128;
    const int u  = b >> 3;
    const int m0 = (u / 3) * 128;
    const int z  = u % 3;
    const ushort_t* Bt = wT + (size_t)z * (DM * DM);
    if (z == 0)      gemm128_body(xb, Bt, Qp, 0, m0, n0);
    else if (z == 1) gemm128_body(xb, Bt, Kp, 0, m0, n0);
    else             gemm128_body(xb, Bt, Vt, 2, m0, n0);
}

__global__ __launch_bounds__(256) void ogemm128(const void* __restrict__ xdet,
                                                const ushort_t* __restrict__ An,
                                                const ushort_t* __restrict__ woT,
                                                void* __restrict__ C) {
    bool f32 = detect_f32((const ushort_t*)xdet);
    const int b = blockIdx.x;
    const int n0 = (b & 7) * 128, m0 = (b >> 3) * 128;
    gemm128_body(An, woT, C, f32 ? 1 : 0, m0, n0);
}

// ---------------------------------------------------------------------------
// Flash attention — R11 verified (89-91 us). FALLBACK path (small workspace).
// ---------------------------------------------------------------------------
__global__ __launch_bounds__(512) void attn_kernel(const ushort_t* __restrict__ Q,
                                                   const ushort_t* __restrict__ Kp,
                                                   const ushort_t* __restrict__ Vt,
                                                   ushort_t* __restrict__ O) {
    __shared__ ushort_t Ks[2][128 * 64];
    __shared__ ushort_t Vs[2][64 * 128];
    __shared__ ushort_t Pt[128 * 128];

    const int b    = blockIdx.x;
    const int h    = 2 * (b & 7) + ((b >> 3) & 1);
    const int px   = b >> 4;
    const int t    = threadIdx.x;
    const int lane = t & 63, wave = t >> 6;
    const int l15  = lane & 15, quad = lane >> 4;
    const float LOG2E  = 1.44269504f;
    const float slope2 = exp2f(-0.5f * (float)(h + 1)) * LOG2E;
    const float c0     = 0.125f * LOG2E;
    const float qd4f   = (float)(quad * 4);

    const int krow = lane >> 3, kgr = (lane & 7) ^ (lane >> 3);
    const int vsub = lane >> 4;
    const int swz = l15 & 7;

    auto stage_load = [&](int buf, int kv0) {
        #pragma unroll
        for (int i = 0; i < 2; ++i) {
            const int j = wave * 2 + i;
            load_lds16(Kp + (size_t)(kv0 + 8 * j + krow) * DM + h * HD + kgr * 8,
                       &Ks[buf][8 * j * 64]);
        }
        #pragma unroll
        for (int i = 0; i < 2; ++i) {
            const int j = wave * 2 + i;
            const int d = 4 * j + vsub;
            const int g = (lane & 15) ^ (4 * (j & 1) + vsub);
            load_lds16(Vt + (size_t)(h * HD + d) * L_SEQ + kv0 + g * 8,
                       &Vs[buf][4 * j * 128]);
        }
    };

    int par = 0;
    stage_load(0, 0);

    #pragma unroll
    for (int half = 0; half < 2; ++half) {
        const int qb = half ? px : (31 - px);
        const int q0 = qb * 128;
        const int qg = q0 + wave * 16 + l15;
        const float qf = (float)qg;
        const int nst = half ? (px + 1) : (32 - px);

        bf16x8 bq[2];
        #pragma unroll
        for (int kt = 0; kt < 2; ++kt)
            bq[kt] = *(const bf16x8*)(Q + (size_t)qg * DM + h * HD + kt * 32 + quad * 8);

        f32x4 acc_o[4] = {};
        float l_r = 0.f;

        for (int s = 0; s < nst; ++s) {
            const int kv0 = s * 128;
            __syncthreads();

            const int nkv0 = (s + 1 < nst) ? (s + 1) * 128 : 0;
            stage_load(par ^ 1, nkv0);

            f32x4 sacc[8];
            #pragma unroll
            for (int mt = 0; mt < 8; ++mt) sacc[mt] = (f32x4){0.f, 0.f, 0.f, 0.f};
            __builtin_amdgcn_s_setprio(1);
            #pragma unroll
            for (int kt = 0; kt < 2; ++kt)
                #pragma unroll
                for (int mt = 0; mt < 8; ++mt) {
                    bf16x8 a = *(const bf16x8*)&Ks[par][(mt * 16 + l15) * 64
                                                        + (((kt * 4 + quad) ^ swz) * 8)];
                    sacc[mt] = __builtin_amdgcn_mfma_f32_16x16x32_bf16(a, bq[kt], sacc[mt], 0, 0, 0);
                }
            __builtin_amdgcn_s_setprio(0);

            const bool diag = (kv0 + 128 > q0);
            const float off = slope2 * ((float)kv0 + qd4f - qf);
            float rs = 0.f;
            #pragma unroll
            for (int mt = 0; mt < 8; ++mt)
                #pragma unroll
                for (int r = 0; r < 4; ++r) {
                    float kvl = (float)(mt * 16 + r);
                    float s2  = fmaf(sacc[mt][r], c0, fmaf(slope2, kvl, off));
                    if (diag) {
                        int kvg = kv0 + mt * 16 + quad * 4 + r;
                        s2 = (kvg <= qg) ? s2 : -1e30f;
                    }
                    float p = ex2(s2);
                    sacc[mt][r] = p;
                    rs += p;
                }
            rs += __shfl_xor(rs, 16);
            rs += __shfl_xor(rs, 32);
            l_r += rs;

            #pragma unroll
            for (int mt = 0; mt < 8; ++mt) {
                union { float f; unsigned u; } a0, a1, a2, a3;
                a0.f = sacc[mt][0]; a1.f = sacc[mt][1];
                a2.f = sacc[mt][2]; a3.f = sacc[mt][3];
                uint2 w;
                w.x = __builtin_amdgcn_perm(a1.u, a0.u, 0x07060302);
                w.y = __builtin_amdgcn_perm(a3.u, a2.u, 0x07060302);
                const int g = mt * 2 + (quad >> 1);
                *(uint2*)&Pt[(wave * 16 + l15) * 128
                             + ((g ^ swz) * 8 + (quad & 1) * 4)] = w;
            }
            __threadfence_block();

            __builtin_amdgcn_s_setprio(1);
            #pragma unroll
            for (int kt = 0; kt < 4; ++kt) {
                bf16x8 a = *(const bf16x8*)&Pt[(wave * 16 + l15) * 128
                                               + (((kt * 4 + quad) ^ swz) * 8)];
                #pragma unroll
                for (int nt = 0; nt < 4; ++nt) {
                    bf16x8 bvv = *(const bf16x8*)&Vs[par][(nt * 16 + l15) * 128
                                                          + (((kt * 4 + quad) ^ swz) * 8)];
                    acc_o[nt] = __builtin_amdgcn_mfma_f32_16x16x32_bf16(a, bvv, acc_o[nt], 0, 0, 0);
                }
            }
            __builtin_amdgcn_s_setprio(0);

            par ^= 1;
        }

        float linv[4];
        #pragma unroll
        for (int r = 0; r < 4; ++r) linv[r] = 1.0f / __shfl(l_r, quad * 4 + r);
        #pragma unroll
        for (int nt = 0; nt < 4; ++nt)
            #pragma unroll
            for (int r = 0; r < 4; ++r) {
                int row = q0 + wave * 16 + quad * 4 + r;
                O[(size_t)row * DM + h * HD + nt * 16 + l15] = f2bf(acc_o[nt][r] * linv[r]);
            }
    }
}

// ---------------------------------------------------------------------------
// R15 attn 2-way SPLIT (verified 70 us): kv-parity decomposition, 2 blocks/CU.
// Fixed-base softmax => partials combine by ADDITION (no max/rescale).
// Grid 512: (b&255) = (h, px); v = b>>8 processes tiles s=v,v+2,... of both
// q-halves. All blocks 16-17 tiles (uniform -> dispatch-order-proof).
// LDS single-buffer Ks 16K + Vs 16K + Pt 32K = 64K -> 2 blocks/CU; paired
// block (same XCD/head) hides staging latency and shares K/V tiles in L2.
// ---------------------------------------------------------------------------
__global__ __launch_bounds__(512, 4) void attn_split(const ushort_t* __restrict__ Q,
                                                     const ushort_t* __restrict__ Kp,
                                                     const ushort_t* __restrict__ Vt,
                                                     float* __restrict__ Op,
                                                     float* __restrict__ Lp) {
    __shared__ ushort_t Ks[128 * 64];
    __shared__ ushort_t Vs[64 * 128];
    __shared__ ushort_t Pt[128 * 128];

    const int b    = blockIdx.x;
    const int bb   = b & 255;
    const int v    = b >> 8;
    const int h    = 2 * (bb & 7) + ((bb >> 3) & 1);
    const int px   = bb >> 4;
    const int t    = threadIdx.x;
    const int lane = t & 63, wave = t >> 6;
    const int l15  = lane & 15, quad = lane >> 4;
    const float LOG2E  = 1.44269504f;
    const float slope2 = exp2f(-0.5f * (float)(h + 1)) * LOG2E;
    const float c0     = 0.125f * LOG2E;
    const float qd4f   = (float)(quad * 4);

    const int krow = lane >> 3, kgr = (lane & 7) ^ (lane >> 3);
    const int vsub = lane >> 4;
    const int swz = l15 & 7;

    float* Opv = Op + (size_t)v * L_SEQ * DM;

    auto stage_load = [&](int kv0) {
        #pragma unroll
        for (int i = 0; i < 2; ++i) {
            const int j = wave * 2 + i;
            load_lds16(Kp + (size_t)(kv0 + 8 * j + krow) * DM + h * HD + kgr * 8,
                       &Ks[8 * j * 64]);
        }
        #pragma unroll
        for (int i = 0; i < 2; ++i) {
            const int j = wave * 2 + i;
            const int d = 4 * j + vsub;
            const int g = (lane & 15) ^ (4 * (j & 1) + vsub);
            load_lds16(Vt + (size_t)(h * HD + d) * L_SEQ + kv0 + g * 8,
                       &Vs[4 * j * 128]);
        }
    };

    #pragma unroll
    for (int half = 0; half < 2; ++half) {
        const int qb = half ? px : (31 - px);
        const int q0 = qb * 128;
        const int qg = q0 + wave * 16 + l15;
        const float qf = (float)qg;
        const int nst = half ? (px + 1) : (32 - px);

        bf16x8 bq[2];
        #pragma unroll
        for (int kt = 0; kt < 2; ++kt)
            bq[kt] = *(const bf16x8*)(Q + (size_t)qg * DM + h * HD + kt * 32 + quad * 8);

        f32x4 acc_o[4] = {};
        float l_r = 0.f;

        for (int s = v; s < nst; s += 2) {
            const int kv0 = s * 128;
            stage_load(kv0);
            __syncthreads();

            f32x4 sacc[8];
            #pragma unroll
            for (int mt = 0; mt < 8; ++mt) sacc[mt] = (f32x4){0.f, 0.f, 0.f, 0.f};
            __builtin_amdgcn_s_setprio(1);
            #pragma unroll
            for (int kt = 0; kt < 2; ++kt)
                #pragma unroll
                for (int mt = 0; mt < 8; ++mt) {
                    bf16x8 a = *(const bf16x8*)&Ks[(mt * 16 + l15) * 64
                                                   + (((kt * 4 + quad) ^ swz) * 8)];
                    sacc[mt] = __builtin_amdgcn_mfma_f32_16x16x32_bf16(a, bq[kt], sacc[mt], 0, 0, 0);
                }
            __builtin_amdgcn_s_setprio(0);

            const bool diag = (kv0 + 128 > q0);
            const float off = slope2 * ((float)kv0 + qd4f - qf);
            float rs = 0.f;
            #pragma unroll
            for (int mt = 0; mt < 8; ++mt)
                #pragma unroll
                for (int r = 0; r < 4; ++r) {
                    float kvl = (float)(mt * 16 + r);
                    float s2  = fmaf(sacc[mt][r], c0, fmaf(slope2, kvl, off));
                    if (diag) {
                        int kvg = kv0 + mt * 16 + quad * 4 + r;
                        s2 = (kvg <= qg) ? s2 : -1e30f;
                    }
                    float p = ex2(s2);
                    sacc[mt][r] = p;
                    rs += p;
                }
            rs += __shfl_xor(rs, 16);
            rs += __shfl_xor(rs, 32);
            l_r += rs;

            #pragma unroll
            for (int mt = 0; mt < 8; ++mt) {
                union { float f; unsigned u; } a0, a1, a2, a3;
                a0.f = sacc[mt][0]; a1.f = sacc[mt][1];
                a2.f = sacc[mt][2]; a3.f = sacc[mt][3];
                uint2 w;
                w.x = __builtin_amdgcn_perm(a1.u, a0.u, 0x07060302);
                w.y = __builtin_amdgcn_perm(a3.u, a2.u, 0x07060302);
                const int g = mt * 2 + (quad >> 1);
                *(uint2*)&Pt[(wave * 16 + l15) * 128
                             + ((g ^ swz) * 8 + (quad & 1) * 4)] = w;
            }
            __threadfence_block();

            __builtin_amdgcn_s_setprio(1);
            #pragma unroll
            for (int kt = 0; kt < 4; ++kt) {
                bf16x8 a = *(const bf16x8*)&Pt[(wave * 16 + l15) * 128
                                               + (((kt * 4 + quad) ^ swz) * 8)];
                #pragma unroll
                for (int nt = 0; nt < 4; ++nt) {
                    bf16x8 bvv = *(const bf16x8*)&Vs[(nt * 16 + l15) * 128
                                                     + (((kt * 4 + quad) ^ swz) * 8)];
                    acc_o[nt] = __builtin_amdgcn_mfma_f32_16x16x32_bf16(a, bvv, acc_o[nt], 0, 0, 0);
                }
            }
            __builtin_amdgcn_s_setprio(0);

            __syncthreads();
        }

        #pragma unroll
        for (int nt = 0; nt < 4; ++nt)
            #pragma unroll
            for (int r = 0; r < 4; ++r) {
                int row = q0 + wave * 16 + quad * 4 + r;
                Opv[(size_t)row * DM + h * HD + nt * 16 + l15] = acc_o[nt][r];
            }
        if (quad == 0)
            Lp[(size_t)v * (NH * L_SEQ) + (size_t)h * L_SEQ + qg] = l_r;
    }
}

// combine: An = (O0 + O1) / (l0 + l1), bf16. 2048 blocks x 256 thr x 8 elems.
__global__ __launch_bounds__(256) void attn_combine(const float* __restrict__ Op,
                                                    const float* __restrict__ Lp,
                                                    ushort_t* __restrict__ An) {
    const int i = (blockIdx.x * 256 + threadIdx.x) * 8;
    const int row = i >> 10;
    const int h   = (i & 1023) >> 6;
    const float l0 = Lp[(size_t)h * L_SEQ + row];
    const float l1 = Lp[(size_t)NH * L_SEQ + (size_t)h * L_SEQ + row];
    const float linv = 1.0f / (l0 + l1);
    const size_t V1 = (size_t)L_SEQ * DM;
    float4 a0 = *(const float4*)(Op + i);
    float4 a1 = *(const float4*)(Op + i + 4);
    float4 b0 = *(const float4*)(Op + V1 + i);
    float4 b1 = *(const float4*)(Op + V1 + i + 4);
    uint4 u;
    u.x = cvt_pk_bf16((a0.x + b0.x) * linv, (a0.y + b0.y) * linv);
    u.y = cvt_pk_bf16((a0.z + b0.z) * linv, (a0.w + b0.w) * linv);
    u.z = cvt_pk_bf16((a1.x + b1.x) * linv, (a1.y + b1.y) * linv);
    u.w = cvt_pk_bf16((a1.z + b1.z) * linv, (a1.w + b1.w) * linv);
    *(uint4*)(An + i) = u;
}

// ---------------------------------------------------------------------------
extern "C" void kernel_launch(void* const* d_in, const int* in_sizes, int n_in,
                              void* d_out, int out_size, void* d_ws, size_t ws_size,
                              hipStream_t stream) {
    const void* x  = d_in[0];
    const void* wq = d_in[1];
    const void* wk = d_in[2];
    const void* wv = d_in[3];
    const void* wo = d_in[4];

    const size_t SZ = (size_t)L_SEQ * DM;   // 4M elems
    const size_t WZ = (size_t)DM * DM;      // 1M elems
    ushort_t* xb = (ushort_t*)d_ws;         // 8 MB
    ushort_t* wT = xb + SZ;                 // 4 x 2 MB
    ushort_t* Qp = wT + 4 * WZ;             // 8 MB
    ushort_t* Kp = Qp + SZ;                 // 8 MB
    ushort_t* Vt = Kp + SZ;                 // 8 MB  -> 40 MB so far
    ushort_t* An = xb;                      // xb dead after qkv -> safe alias

    float* Op = (float*)(Vt + SZ);          // 2 x 16 MB partial O (f32)
    float* Lp = Op + 2 * SZ;                // 2 x 256 KB partial l
    const size_t need = 40ull * 1024 * 1024 + 2 * SZ * 4 + 2ull * NH * L_SEQ * 4;

    convert_all<<<dim3(16, 16, 5), 256, 0, stream>>>(x, wq, wk, wv, wo, xb, wT);
    qkv128<<<768, 256, 0, stream>>>(xb, wT, Qp, Kp, Vt);
    if (ws_size >= need) {
        attn_split<<<512, 512, 0, stream>>>(Qp, Kp, Vt, Op, Lp);
        attn_combine<<<2048, 256, 0, stream>>>(Op, Lp, An);
    } else {
        attn_kernel<<<256, 512, 0, stream>>>(Qp, Kp, Vt, An);
    }
    ogemm128<<<256, 256, 0, stream>>>(x, An, wT + 3 * WZ, d_out);
}